// Round 1
// baseline (2517.375 us; speedup 1.0000x reference)
//
#include <hip/hip_runtime.h>
#include <hip/hip_cooperative_groups.h>
#include <math.h>

namespace cg = cooperative_groups;

// B=4096, R=130, T=200, Q=64. f16 MFMA 16x16x32 everywhere, fp32 accum/stats.
// R4 (this round): single cooperative mega-kernel, 18 grid syncs.
//  - __launch_bounds__(256,4): cap 128 VGPR -> 4 blocks/CU (16 waves/CU).
//  - k_in phase: direct global->reg A-frags (no LDS staging pass).
//  - Asoft phase: flash-style 3-pass (max/sum/emit) recomputing the 18-MFMA
//    tile each pass; removes acc[9] (-36 VGPR) and ~68 exp per m-tile.
//  - stats phases inline (blocks 0..129), others park at the grid sync.

typedef _Float16 f16;
typedef _Float16 f16x8 __attribute__((ext_vector_type(8)));
typedef float f32x4 __attribute__((ext_vector_type(4)));

#define MFMA16(a, b, c) __builtin_amdgcn_mfma_f32_16x16x32_f16((a), (b), (c), 0, 0, 0)

struct Params {
  const float *X, *THR, *WQ, *BQ, *GT, *BT;
  const float *W1, *Bb1, *G1, *BE1;
  const float *W2, *Bb2, *G2, *BE2;
  const float *W3, *Bb3, *G3, *BE3;
  const float *W4, *Bb4, *G4, *BE4;
  const float *W5, *Bb5, *G5, *BE5;
  const float *W6, *Bb6, *G6, *BE6;
  const float *WM, *BM;
  f16 *A16, *qk, *xw1, *wf;
  float *Z1, *Z2, *Z3, *Z4, *Z5, *Z6, *sp, *ac;
  float *out;
};

// Gather the 18 B-fragments (9 n-tiles x 2 k-halves) for the reshape-K matmul.
// B[k=q][n-col=s]: element = flat[q*130+s]; s>=130 -> 0.
__device__ __forceinline__ void gather_bfrags(const f16* qf, int mrow, int quad,
                                              f16x8 bf[9][2])
{
#pragma unroll
  for (int n = 0; n < 9; n++) {
    const int s = n * 16 + mrow;
    const bool ok = (s < 130);
#pragma unroll
    for (int kh = 0; kh < 2; kh++) {
      f16x8 t;
#pragma unroll
      for (int j = 0; j < 8; j++) {
        int q = kh * 32 + quad * 8 + j;
        t[j] = ok ? qf[q * 130 + s] : (f16)0.f;
      }
      bf[n][kh] = t;
    }
  }
}

// ---------------- phase: X(532480x200) @ wf^T -> qk f16, xw1 f16 (direct-reg)
__device__ void kin_phase(const float* __restrict__ X, const f16* __restrict__ wf,
                          const float* __restrict__ bq, f16* __restrict__ qk,
                          f16* __restrict__ xw1, int bid, int nb, int tid)
{
  const int lane = tid & 63, wv = tid >> 6, mrow = lane & 15, quad = lane >> 4;
  const int cbase = quad * 8;
  for (int t = bid; t < 8320; t += nb) {
    const size_t m0 = (size_t)t * 64;
    const float* xr = X + (m0 + wv * 16 + mrow) * 200;
    f32x4 acc[5];
#pragma unroll
    for (int n = 0; n < 5; n++) acc[n] = (f32x4){0.f, 0.f, 0.f, 0.f};
#pragma unroll
    for (int k0 = 0; k0 < 224; k0 += 32) {
      const int c0 = k0 + cbase;
      f16x8 af;
#pragma unroll
      for (int j = 0; j < 8; j++) af[j] = (f16)0.f;
      if (c0 < 200) {                         // only quad>0 at k0=192 skips
        float4 v0 = *(const float4*)(xr + c0);
        float4 v1 = *(const float4*)(xr + c0 + 4);
        float vv[8];
        *(float4*)&vv[0] = v0;
        *(float4*)&vv[4] = v1;
#pragma unroll
        for (int j = 0; j < 8; j++) {
          float x = vv[j];
          af[j] = (f16)((x != x) ? 0.f : x);  // NaN-clean + cvt
        }
      }
#pragma unroll
      for (int n = 0; n < 5; n++)
        acc[n] = MFMA16(af, *(const f16x8*)(wf + (n * 16 + mrow) * 224 + c0), acc[n]);
    }
    const size_t rbase = m0 + wv * 16;
#pragma unroll
    for (int n = 0; n < 4; n++) {             // qk (+bq)
      int col = n * 16 + mrow;
      float bqv = bq[col];
#pragma unroll
      for (int i = 0; i < 4; i++)
        qk[(rbase + quad * 4 + i) * 64 + col] = (f16)(acc[n][i] + bqv);
    }
#pragma unroll
    for (int i = 0; i < 4; i++)               // xw1, no bias (added post-A-matmul)
      xw1[(rbase + quad * 4 + i) * 16 + mrow] = (f16)acc[4][i];
  }
}

// ---------------- phase: rel tiles (MFMA), emit BN partial sums only
__device__ void relstats_phase(const f16* __restrict__ qk, float* __restrict__ sp,
                               f16* qf, int bid, int nb, int tid)
{
  const int lane = tid & 63, wv = tid >> 6, mrow = lane & 15, quad = lane >> 4;
  for (int b = bid; b < 4096; b += nb) {
    __syncthreads();                          // protect qf reuse across iters
    const f16* qb = qk + (size_t)b * 8320;
    for (int i = tid; i < 1040; i += 256)
      *(f16x8*)&qf[i * 8] = *(const f16x8*)(qb + i * 8);
    __syncthreads();
    f16x8 bf[9][2];
    gather_bfrags(qf, mrow, quad, bf);
    for (int m = wv; m < 9; m += 4) {
      const f16* arow = qb + (m * 16 + mrow) * 64 + quad * 8;
      f16x8 af0 = *(const f16x8*)arow;
      f16x8 af1 = *(const f16x8*)(arow + 32);
      float p1[4] = {0, 0, 0, 0}, p2[4] = {0, 0, 0, 0};
#pragma unroll
      for (int n = 0; n < 9; n++) {
        f32x4 acc = (f32x4){0.f, 0.f, 0.f, 0.f};
        acc = MFMA16(af0, bf[n][0], acc);
        acc = MFMA16(af1, bf[n][1], acc);
#pragma unroll
        for (int i = 0; i < 4; i++) { float v = acc[i]; p1[i] += v; p2[i] += v * v; }
      }
#pragma unroll
      for (int i = 0; i < 4; i++)
#pragma unroll
        for (int msk = 1; msk <= 8; msk <<= 1) {
          p1[i] += __shfl_xor(p1[i], msk); p2[i] += __shfl_xor(p2[i], msk);
        }
      if (mrow == 0) {
#pragma unroll
        for (int i = 0; i < 4; i++) {
          int r = m * 16 + quad * 4 + i;
          if (r < 130) {
            sp[(size_t)r * 4096 + b] = p1[i];
            sp[130 * 4096 + (size_t)r * 4096 + b] = p2[i];
          }
        }
      }
    }
  }
}

// ---------------- phase: reduce partials -> affine a,c (blocks 0..129)
__device__ void stats_phase(const float* __restrict__ sp, const float* __restrict__ g,
                            const float* __restrict__ be, float invN,
                            float* __restrict__ acOut, float* rr, int bid, int tid)
{
  if (bid < 130) {
    const int r = bid;
    float s1 = 0.f, s2 = 0.f;
    const float* p1 = sp + (size_t)r * 4096;
    const float* p2 = sp + 130 * 4096 + (size_t)r * 4096;
    for (int j = tid; j < 4096; j += 256) { s1 += p1[j]; s2 += p2[j]; }
#pragma unroll
    for (int m = 1; m <= 32; m <<= 1) { s1 += __shfl_xor(s1, m); s2 += __shfl_xor(s2, m); }
    if ((tid & 63) == 0) { rr[tid >> 6] = s1; rr[4 + (tid >> 6)] = s2; }
    __syncthreads();
    if (tid == 0) {
      float S1 = rr[0] + rr[1] + rr[2] + rr[3];
      float S2 = rr[4] + rr[5] + rr[6] + rr[7];
      float mean = S1 * invN;
      float var = S2 * invN - mean * mean;
      float a = g[r] * rsqrtf(var + 1e-5f);
      acOut[r] = a;
      acOut[130 + r] = be[r] - mean * a;
    }
  }
}

// ---------------- phase: rel (3 MFMA passes), affine, softmax, relu(x-thr),
// A -> f16 [b][130][136] (cols 130-135 zeroed)
__device__ void asoft_phase(const f16* __restrict__ qk, const float* __restrict__ ac0,
                            float thr, f16* __restrict__ A16, f16* qf,
                            int bid, int nb, int tid)
{
  const int lane = tid & 63, wv = tid >> 6, mrow = lane & 15, quad = lane >> 4;
  for (int b = bid; b < 4096; b += nb) {
    __syncthreads();
    const f16* qb = qk + (size_t)b * 8320;
    for (int i = tid; i < 1040; i += 256)
      *(f16x8*)&qf[i * 8] = *(const f16x8*)(qb + i * 8);
    __syncthreads();
    f16x8 bf[9][2];
    gather_bfrags(qf, mrow, quad, bf);
    f16* Ab = A16 + (size_t)b * 17680;        // row stride 136
    for (int m = wv; m < 9; m += 4) {
      float a4[4], c4[4];
#pragma unroll
      for (int i = 0; i < 4; i++) {
        int r = m * 16 + quad * 4 + i;
        a4[i] = (r < 130) ? ac0[r] : 0.f;
        c4[i] = (r < 130) ? ac0[130 + r] : 0.f;
      }
      const f16* arow = qb + (m * 16 + mrow) * 64 + quad * 8;
      f16x8 af0 = *(const f16x8*)arow;
      f16x8 af1 = *(const f16x8*)(arow + 32);
      // pass 1: row max
      float mx[4] = {-3e38f, -3e38f, -3e38f, -3e38f};
#pragma unroll
      for (int n = 0; n < 9; n++) {
        f32x4 acc = (f32x4){0.f, 0.f, 0.f, 0.f};
        acc = MFMA16(af0, bf[n][0], acc);
        acc = MFMA16(af1, bf[n][1], acc);
        const bool valid = (n * 16 + mrow) < 130;
#pragma unroll
        for (int i = 0; i < 4; i++) {
          float v = a4[i] * acc[i] + c4[i];
          if (valid) mx[i] = fmaxf(mx[i], v);
        }
      }
#pragma unroll
      for (int i = 0; i < 4; i++)
#pragma unroll
        for (int msk = 1; msk <= 8; msk <<= 1)
          mx[i] = fmaxf(mx[i], __shfl_xor(mx[i], msk));
      // pass 2: exp-sum (final max known -> no rescale)
      float sm[4] = {0.f, 0.f, 0.f, 0.f};
#pragma unroll
      for (int n = 0; n < 9; n++) {
        f32x4 acc = (f32x4){0.f, 0.f, 0.f, 0.f};
        acc = MFMA16(af0, bf[n][0], acc);
        acc = MFMA16(af1, bf[n][1], acc);
        const bool valid = (n * 16 + mrow) < 130;
#pragma unroll
        for (int i = 0; i < 4; i++) {
          float v = a4[i] * acc[i] + c4[i];
          if (valid) sm[i] += __expf(v - mx[i]);
        }
      }
#pragma unroll
      for (int i = 0; i < 4; i++) {
#pragma unroll
        for (int msk = 1; msk <= 8; msk <<= 1)
          sm[i] += __shfl_xor(sm[i], msk);
        sm[i] = 1.f / sm[i];
      }
      // pass 3: emit A f16
#pragma unroll
      for (int n = 0; n < 9; n++) {
        f32x4 acc = (f32x4){0.f, 0.f, 0.f, 0.f};
        acc = MFMA16(af0, bf[n][0], acc);
        acc = MFMA16(af1, bf[n][1], acc);
        const int col = n * 16 + mrow;
#pragma unroll
        for (int i = 0; i < 4; i++) {
          int r = m * 16 + quad * 4 + i;
          if (r < 130) {
            if (col < 130) {
              float v = a4[i] * acc[i] + c4[i];
              Ab[r * 136 + col] = (f16)fmaxf(__expf(v - mx[i]) * sm[i] - thr, 0.f);
            } else if (col < 136) {
              Ab[r * 136 + col] = (f16)0.f;
            }
          }
        }
      }
    }
  }
}

// ---------------- phase: Z = A @ g + b; A-frags direct from global, gT in LDS
template <int FI, int FO, bool RES, bool G1f>
__device__ void gcn_phase(const f16* __restrict__ A16, const float* __restrict__ ZP,
                          const float* __restrict__ ZQ, const f16* __restrict__ xw1,
                          const float* __restrict__ acP, const float* __restrict__ acQ,
                          const float* __restrict__ wmat, const float* __restrict__ bb,
                          float* __restrict__ Zout, float* __restrict__ sp,
                          f16* gT, int bid, int nb, int tid)
{
  const int lane = tid & 63, wv = tid >> 6, mrow = lane & 15, quad = lane >> 4;
  for (int b = bid; b < 4096; b += nb) {
    __syncthreads();                          // protect gT reuse across iters
    for (int i = tid; i < 1344; i += 256) ((float*)gT)[i] = 0.f;
    __syncthreads();
    if constexpr (G1f) {
      for (int i = tid; i < 2080; i += 256) {
        int s = i >> 4, f = i & 15;
        gT[f * 168 + s] = xw1[(size_t)b * 2080 + i];
      }
    } else {
      if (tid < 130) {
        const int r = tid;
        float h[FI];
        const float* zp = ZP + ((size_t)b * 130 + r) * FI;
        const float aP = acP[r], cP = acP[130 + r];
#pragma unroll
        for (int i = 0; i < FI; i++) h[i] = fmaxf(aP * zp[i] + cP, 0.f);
        if constexpr (RES) {
          const float* zq = ZQ + ((size_t)b * 130 + r) * FI;
          const float aQ = acQ[r], cQ = acQ[130 + r];
#pragma unroll
          for (int i = 0; i < FI; i++) h[i] += fmaxf(aQ * zq[i] + cQ, 0.f);
        }
#pragma unroll
        for (int k = 0; k < FO; k++) {
          float s = 0.f;
#pragma unroll
          for (int i = 0; i < FI; i++) s += h[i] * wmat[k * FI + i];
          gT[k * 168 + r] = (f16)s;           // bias NOT here (added post-A)
        }
      }
    }
    __syncthreads();
    f16x8 bfr[5];                             // B-frags cached (k=0..159; >=130 zero)
#pragma unroll
    for (int kk = 0; kk < 5; kk++)
      bfr[kk] = *(const f16x8*)&gT[mrow * 168 + kk * 32 + quad * 8];
    const f16* Ab = A16 + (size_t)b * 17680;
    for (int m = wv; m < 9; m += 4) {
      const f16* arow = Ab + (m * 16 + mrow) * 136 + quad * 8;
      f32x4 acc = (f32x4){0.f, 0.f, 0.f, 0.f};
#pragma unroll
      for (int kk = 0; kk < 5; kk++)          // k>=136 reads next row, B=0 there
        acc = MFMA16(*(const f16x8*)(arow + kk * 32), bfr[kk], acc);
      const int col = mrow;
      const float bk = (col < FO) ? bb[col] : 0.f;
      float p1[4], p2[4];
#pragma unroll
      for (int i = 0; i < 4; i++) {
        int r = m * 16 + quad * 4 + i;
        float v = (col < FO) ? acc[i] + bk : 0.f;
        if (col < FO && r < 130)
          Zout[((size_t)b * 130 + r) * FO + col] = v;
        p1[i] = v; p2[i] = v * v;
      }
#pragma unroll
      for (int i = 0; i < 4; i++)
#pragma unroll
        for (int msk = 1; msk <= 8; msk <<= 1) {
          p1[i] += __shfl_xor(p1[i], msk); p2[i] += __shfl_xor(p2[i], msk);
        }
      if (mrow == 0) {
#pragma unroll
        for (int i = 0; i < 4; i++) {
          int r = m * 16 + quad * 4 + i;
          if (r < 130) {
            sp[(size_t)r * 4096 + b] = p1[i];
            sp[130 * 4096 + (size_t)r * 4096 + b] = p2[i];
          }
        }
      }
    }
  }
}

// ---------------- phase: mlp
__device__ void mlp_phase(const float* __restrict__ Z5, const float* __restrict__ Z6,
                          const float* __restrict__ ac5, const float* __restrict__ ac6,
                          const float* __restrict__ wm, const float* __restrict__ bm,
                          float* __restrict__ out, int bid, int nb, int tid)
{
  const int lane = tid & 63, wv = tid >> 6;
  for (int b = bid * 4 + wv; b < 4096; b += nb * 4) {
    const float* z5 = Z5 + (size_t)b * 260;
    const float* z6 = Z6 + (size_t)b * 260;
    float p0 = 0.f, p1 = 0.f;
#pragma unroll
    for (int j = 0; j < 5; j++) {
      int i = lane + 64 * j;
      if (i < 260) {
        int r = i >> 1;
        float h = fmaxf(ac6[r] * z6[i] + ac6[130 + r], 0.f)
                + fmaxf(ac5[r] * z5[i] + ac5[130 + r], 0.f);
        p0 += h * wm[i];
        p1 += h * wm[260 + i];
      }
    }
#pragma unroll
    for (int m = 1; m <= 32; m <<= 1) { p0 += __shfl_xor(p0, m); p1 += __shfl_xor(p1, m); }
    if (lane == 0) {
      out[(size_t)b * 2] = fmaxf(p0 + bm[0], 0.f);
      out[(size_t)b * 2 + 1] = fmaxf(p1 + bm[1], 0.f);
    }
  }
}

// ---------------- the mega-kernel
__global__ __launch_bounds__(256, 4) void mega(Params P, int nb)
{
  cg::grid_group grid = cg::this_grid();
  __shared__ __align__(16) char smemraw[16640];   // qf(16640B) >= gT(5376B) >= rr(32B)
  f16* qf = (f16*)smemraw;
  f16* gT = (f16*)smemraw;
  float* rr = (float*)smemraw;
  const int bid = blockIdx.x, tid = threadIdx.x;

  // w_prep: [wq(64x200) | w1(16x200)] -> f16 wf[80][224], K zero-pad
  for (int idx = bid * 256 + tid; idx < 80 * 224; idx += nb * 256) {
    int f = idx / 224, k = idx - f * 224;
    float v = 0.f;
    if (k < 200) v = (f < 64) ? P.WQ[f * 200 + k] : P.W1[(f - 64) * 200 + k];
    P.wf[idx] = (f16)v;
  }
  grid.sync();
  kin_phase(P.X, P.wf, P.BQ, P.qk, P.xw1, bid, nb, tid);
  grid.sync();
  relstats_phase(P.qk, P.sp, qf, bid, nb, tid);
  grid.sync();
  stats_phase(P.sp, P.GT, P.BT, 1.f / 532480.f, P.ac, rr, bid, tid);
  grid.sync();
  const float thr = *P.THR;
  asoft_phase(P.qk, P.ac, thr, P.A16, qf, bid, nb, tid);
  grid.sync();
  gcn_phase<16, 16, false, true>(P.A16, nullptr, nullptr, P.xw1, nullptr, nullptr,
                                 nullptr, P.Bb1, P.Z1, P.sp, gT, bid, nb, tid);
  grid.sync();
  stats_phase(P.sp, P.G1, P.BE1, 1.f / 65536.f, P.ac + 260, rr, bid, tid);
  grid.sync();
  gcn_phase<16, 16, false, false>(P.A16, P.Z1, nullptr, nullptr, P.ac + 260, nullptr,
                                  P.W2, P.Bb2, P.Z2, P.sp, gT, bid, nb, tid);
  grid.sync();
  stats_phase(P.sp, P.G2, P.BE2, 1.f / 65536.f, P.ac + 520, rr, bid, tid);
  grid.sync();
  gcn_phase<16, 4, true, false>(P.A16, P.Z2, P.Z1, nullptr, P.ac + 520, P.ac + 260,
                                P.W3, P.Bb3, P.Z3, P.sp, gT, bid, nb, tid);
  grid.sync();
  stats_phase(P.sp, P.G3, P.BE3, 1.f / 16384.f, P.ac + 780, rr, bid, tid);
  grid.sync();
  gcn_phase<4, 4, false, false>(P.A16, P.Z3, nullptr, nullptr, P.ac + 780, nullptr,
                                P.W4, P.Bb4, P.Z4, P.sp, gT, bid, nb, tid);
  grid.sync();
  stats_phase(P.sp, P.G4, P.BE4, 1.f / 16384.f, P.ac + 1040, rr, bid, tid);
  grid.sync();
  gcn_phase<4, 2, true, false>(P.A16, P.Z4, P.Z3, nullptr, P.ac + 1040, P.ac + 780,
                               P.W5, P.Bb5, P.Z5, P.sp, gT, bid, nb, tid);
  grid.sync();
  stats_phase(P.sp, P.G5, P.BE5, 1.f / 8192.f, P.ac + 1300, rr, bid, tid);
  grid.sync();
  gcn_phase<2, 2, false, false>(P.A16, P.Z5, nullptr, nullptr, P.ac + 1300, nullptr,
                                P.W6, P.Bb6, P.Z6, P.sp, gT, bid, nb, tid);
  grid.sync();
  stats_phase(P.sp, P.G6, P.BE6, 1.f / 8192.f, P.ac + 1560, rr, bid, tid);
  grid.sync();
  mlp_phase(P.Z5, P.Z6, P.ac + 1300, P.ac + 1560, P.WM, P.BM, P.out, bid, nb, tid);
}

extern "C" void kernel_launch(void* const* d_in, const int* in_sizes, int n_in,
                              void* d_out, int out_size, void* d_ws, size_t ws_size,
                              hipStream_t stream) {
  Params P;
  P.X   = (const float*)d_in[0];
  P.THR = (const float*)d_in[1];
  P.WQ  = (const float*)d_in[2];
  P.BQ  = (const float*)d_in[3];
  P.GT  = (const float*)d_in[4];
  P.BT  = (const float*)d_in[5];
  P.W1 = (const float*)d_in[6];  P.Bb1 = (const float*)d_in[7];
  P.G1 = (const float*)d_in[8];  P.BE1 = (const float*)d_in[9];
  P.W2 = (const float*)d_in[10]; P.Bb2 = (const float*)d_in[11];
  P.G2 = (const float*)d_in[12]; P.BE2 = (const float*)d_in[13];
  P.W3 = (const float*)d_in[14]; P.Bb3 = (const float*)d_in[15];
  P.G3 = (const float*)d_in[16]; P.BE3 = (const float*)d_in[17];
  P.W4 = (const float*)d_in[18]; P.Bb4 = (const float*)d_in[19];
  P.G4 = (const float*)d_in[20]; P.BE4 = (const float*)d_in[21];
  P.W5 = (const float*)d_in[22]; P.Bb5 = (const float*)d_in[23];
  P.G5 = (const float*)d_in[24]; P.BE5 = (const float*)d_in[25];
  P.W6 = (const float*)d_in[26]; P.Bb6 = (const float*)d_in[27];
  P.G6 = (const float*)d_in[28]; P.BE6 = (const float*)d_in[29];
  P.WM = (const float*)d_in[30]; P.BM = (const float*)d_in[31];

  float* ws = (float*)d_ws;
  // Workspace (float units). Total ~82.0M floats = 328 MB.
  P.A16  = (f16*)ws;                          // 4096*130*136 halfs
  P.qk   = (f16*)(ws + 36208640);             // 532480*64 halfs
  P.xw1  = (f16*)(ws + 53248000);             // 532480*16 halfs
  P.wf   = (f16*)(ws + 57507840);             // 80*224 halfs (8960 fl)
  P.Z1 = ws + 57516800;
  P.Z2 = ws + 66036480;
  P.Z3 = ws + 74556160;
  P.Z4 = ws + 76686080;
  P.Z5 = ws + 78816000;
  P.Z6 = ws + 79880960;
  P.sp = ws + 80945920;
  P.ac = ws + 82010880;
  P.out = (float*)d_out;

  int occ = 0;
  hipError_t e = hipOccupancyMaxActiveBlocksPerMultiprocessor(&occ, mega, 256, 0);
  if (e != hipSuccess || occ < 1) occ = 1;
  int nb = occ * 256;                         // MI355X: 256 CUs
  if (nb > 4096) nb = 4096;
  void* args[] = { (void*)&P, (void*)&nb };
  hipLaunchCooperativeKernel((void*)mega, dim3(nb), dim3(256), args, 0, stream);
}

// Round 2
// 2203.627 us; speedup vs baseline: 1.1424x; 1.1424x over previous
//
#include <hip/hip_runtime.h>
#include <hip/hip_cooperative_groups.h>
#include <math.h>

namespace cg = cooperative_groups;

// B=4096, R=130, T=200, Q=64. f16 MFMA 16x16x32 everywhere, fp32 accum/stats.
// R5: cooperative mega-kernel, spill-free redesign.
//  - launch_bounds(256,3): VGPR cap ~170 >> worst-phase need (~120) -> no spills.
//  - B-fragments staged in LDS in MFMA fragment layout (BT): 18 conflict-free
//    ds_read_b128 per tile-row instead of 144 scalar gathers; 8 live B-VGPRs.
//  - Asoft: 2-pass softmax without max-subtraction (BN z-scores, clamp 80).
//  - kin: R3 coalesced LDS-staged version (xs stride 232).

typedef _Float16 f16;
typedef _Float16 f16x4 __attribute__((ext_vector_type(4)));
typedef _Float16 f16x8 __attribute__((ext_vector_type(8)));
typedef float f32x4 __attribute__((ext_vector_type(4)));

#define MFMA16(a, b, c) __builtin_amdgcn_mfma_f32_16x16x32_f16((a), (b), (c), 0, 0, 0)

#define FRAG_STRIDE 528   // f16 elems per fragment slot (1056 B: 16B-aligned, 8-bank shift)

struct Params {
  const float *X, *THR, *WQ, *BQ, *GT, *BT;
  const float *W1, *Bb1, *G1, *BE1;
  const float *W2, *Bb2, *G2, *BE2;
  const float *W3, *Bb3, *G3, *BE3;
  const float *W4, *Bb4, *G4, *BE4;
  const float *W5, *Bb5, *G5, *BE5;
  const float *W6, *Bb6, *G6, *BE6;
  const float *WM, *BM;
  f16 *A16, *qk, *xw1, *wf;
  float *Z1, *Z2, *Z3, *Z4, *Z5, *Z6, *sp, *ac;
  float *out;
};

// Stage per-batch qk flat (8320 halves) into MFMA B-fragment layout:
// B[k=q][col=s] = flat[q*130+s].  Fragment (n,kh) holds cols n*16..+15,
// k = kh*32 + quad*8 + j; lane = quad*16 + mrow holds 8 contiguous halves.
// Rows s>=130 (n=8, mrow>=2) zeroed.
__device__ __forceinline__ void stage_bfrag(const f16* __restrict__ qb,
                                            f16* __restrict__ BT, int tid)
{
  for (int i = tid; i < 128; i += 256) {      // zero n=8 fragments (1024 halves)
    int kh = i >> 6;
    *(float4*)&BT[(16 + kh) * FRAG_STRIDE + (i & 63) * 8] = make_float4(0.f, 0.f, 0.f, 0.f);
  }
  __syncthreads();
  for (int i = tid; i < 1040; i += 256) {
    f16x8 v = *(const f16x8*)(qb + i * 8);
    int L = i * 8;
    int q = L / 130;
    int s = L - q * 130;
#pragma unroll
    for (int j = 0; j < 8; j++) {
      int frag = ((s >> 4) << 1) + (q >> 5);
      int lane = ((q >> 3) & 3) * 16 + (s & 15);
      BT[frag * FRAG_STRIDE + lane * 8 + (q & 7)] = v[j];
      s++; if (s == 130) { s = 0; q++; }
    }
  }
}

// ---------------- phase: X(532480x200) @ wf^T -> qk f16, xw1 f16 (LDS-staged)
__device__ void kin_phase(const float* __restrict__ X, const f16* __restrict__ wf,
                          const float* __restrict__ bq, f16* __restrict__ qk,
                          f16* __restrict__ xw1, f16* xs, int bid, int nb, int tid)
{
  const int lane = tid & 63, wv = tid >> 6, mrow = lane & 15, quad = lane >> 4;
  for (int t = bid; t < 8320; t += nb) {
    __syncthreads();                          // protect xs reuse across iters
    const size_t m0 = (size_t)t * 64;
    {                                         // zero K-pad cols 200..231
      int r = tid >> 2, j = tid & 3;
      *(float4*)&xs[r * 232 + 200 + j * 8] = make_float4(0, 0, 0, 0);
    }
    const float4* xsrc = (const float4*)(X + m0 * 200);
    for (int i = tid; i < 3200; i += 256) {   // NaN-clean + cvt f16, coalesced
      int r = i / 50, c = i - (i / 50) * 50;
      float4 v = xsrc[i];
      v.x = (v.x != v.x) ? 0.f : v.x;
      v.y = (v.y != v.y) ? 0.f : v.y;
      v.z = (v.z != v.z) ? 0.f : v.z;
      v.w = (v.w != v.w) ? 0.f : v.w;
      f16x4 h; h[0] = (f16)v.x; h[1] = (f16)v.y; h[2] = (f16)v.z; h[3] = (f16)v.w;
      *(f16x4*)&xs[r * 232 + c * 4] = h;
    }
    __syncthreads();
    f32x4 acc[5];
#pragma unroll
    for (int n = 0; n < 5; n++) acc[n] = (f32x4){0.f, 0.f, 0.f, 0.f};
    const f16* xrow = &xs[(wv * 16 + mrow) * 232 + quad * 8];
    const f16* wrow = wf + mrow * 224 + quad * 8;   // B-frags from global (L2-hot)
#pragma unroll
    for (int k0 = 0; k0 < 224; k0 += 32) {
      f16x8 af = *(const f16x8*)(xrow + k0);
#pragma unroll
      for (int n = 0; n < 5; n++)
        acc[n] = MFMA16(af, *(const f16x8*)(wrow + n * 3584 + k0), acc[n]);
    }
    const size_t rbase = m0 + wv * 16;
#pragma unroll
    for (int n = 0; n < 4; n++) {             // qk (+bq)
      int col = n * 16 + mrow;
      float bqv = bq[col];
#pragma unroll
      for (int i = 0; i < 4; i++)
        qk[(rbase + quad * 4 + i) * 64 + col] = (f16)(acc[n][i] + bqv);
    }
#pragma unroll
    for (int i = 0; i < 4; i++)               // xw1, no bias (added post-A-matmul)
      xw1[(rbase + quad * 4 + i) * 16 + mrow] = (f16)acc[4][i];
  }
}

// ---------------- phase: rel tiles (MFMA), emit BN partial sums only
__device__ void relstats_phase(const f16* __restrict__ qk, float* __restrict__ sp,
                               f16* BT, int bid, int nb, int tid)
{
  const int lane = tid & 63, wv = tid >> 6, mrow = lane & 15, quad = lane >> 4;
  for (int b = bid; b < 4096; b += nb) {
    __syncthreads();                          // protect BT reuse across iters
    const f16* qb = qk + (size_t)b * 8320;
    stage_bfrag(qb, BT, tid);
    __syncthreads();
    float p1[3][4], p2[3][4];
#pragma unroll
    for (int mi = 0; mi < 3; mi++)
#pragma unroll
      for (int i = 0; i < 4; i++) { p1[mi][i] = 0.f; p2[mi][i] = 0.f; }
#pragma unroll
    for (int mi = 0; mi < 3; mi++) {
      const int m = wv + mi * 4;
      if (m < 9) {
        const f16* arow = qb + (m * 16 + mrow) * 64 + quad * 8;
        f16x8 af0 = *(const f16x8*)arow;
        f16x8 af1 = *(const f16x8*)(arow + 32);
#pragma unroll
        for (int n = 0; n < 9; n++) {
          f16x8 bf0 = *(const f16x8*)&BT[(n * 2 + 0) * FRAG_STRIDE + lane * 8];
          f16x8 bf1 = *(const f16x8*)&BT[(n * 2 + 1) * FRAG_STRIDE + lane * 8];
          f32x4 acc = (f32x4){0.f, 0.f, 0.f, 0.f};
          acc = MFMA16(af0, bf0, acc);
          acc = MFMA16(af1, bf1, acc);
#pragma unroll
          for (int i = 0; i < 4; i++) { float v = acc[i]; p1[mi][i] += v; p2[mi][i] += v * v; }
        }
      }
    }
#pragma unroll
    for (int mi = 0; mi < 3; mi++) {
      const int m = wv + mi * 4;
      if (m < 9) {
#pragma unroll
        for (int i = 0; i < 4; i++)
#pragma unroll
          for (int msk = 1; msk <= 8; msk <<= 1) {
            p1[mi][i] += __shfl_xor(p1[mi][i], msk);
            p2[mi][i] += __shfl_xor(p2[mi][i], msk);
          }
        if (mrow == 0) {
#pragma unroll
          for (int i = 0; i < 4; i++) {
            int r = m * 16 + quad * 4 + i;
            if (r < 130) {
              sp[(size_t)r * 4096 + b] = p1[mi][i];
              sp[130 * 4096 + (size_t)r * 4096 + b] = p2[mi][i];
            }
          }
        }
      }
    }
  }
}

// ---------------- phase: reduce partials -> affine a,c (blocks 0..129)
__device__ void stats_phase(const float* __restrict__ sp, const float* __restrict__ g,
                            const float* __restrict__ be, float invN,
                            float* __restrict__ acOut, float* rr, int bid, int tid)
{
  if (bid < 130) {
    const int r = bid;
    float s1 = 0.f, s2 = 0.f;
    const float* p1 = sp + (size_t)r * 4096;
    const float* p2 = sp + 130 * 4096 + (size_t)r * 4096;
    for (int j = tid; j < 4096; j += 256) { s1 += p1[j]; s2 += p2[j]; }
#pragma unroll
    for (int m = 1; m <= 32; m <<= 1) { s1 += __shfl_xor(s1, m); s2 += __shfl_xor(s2, m); }
    if ((tid & 63) == 0) { rr[tid >> 6] = s1; rr[4 + (tid >> 6)] = s2; }
    __syncthreads();
    if (tid == 0) {
      float S1 = rr[0] + rr[1] + rr[2] + rr[3];
      float S2 = rr[4] + rr[5] + rr[6] + rr[7];
      float mean = S1 * invN;
      float var = S2 * invN - mean * mean;
      float a = g[r] * rsqrtf(var + 1e-5f);
      acOut[r] = a;
      acOut[130 + r] = be[r] - mean * a;
    }
  }
}

// ---------------- phase: rel (2-pass, no max-sub), affine, softmax,
// relu(x-thr), A -> f16 [b][130][136] (cols 130-135 zeroed)
__device__ void asoft_phase(const f16* __restrict__ qk, const float* __restrict__ ac0,
                            float thr, f16* __restrict__ A16, f16* BT,
                            int bid, int nb, int tid)
{
  const int lane = tid & 63, wv = tid >> 6, mrow = lane & 15, quad = lane >> 4;
  for (int b = bid; b < 4096; b += nb) {
    __syncthreads();
    const f16* qb = qk + (size_t)b * 8320;
    stage_bfrag(qb, BT, tid);
    __syncthreads();
    f16* Ab = A16 + (size_t)b * 17680;        // row stride 136
    float a4[3][4], c4[3][4], sm[3][4];
    f16x8 afr[3][2];
#pragma unroll
    for (int mi = 0; mi < 3; mi++) {
      const int m = wv + mi * 4;
      if (m < 9) {
#pragma unroll
        for (int i = 0; i < 4; i++) {
          int r = m * 16 + quad * 4 + i;
          a4[mi][i] = (r < 130) ? ac0[r] : 0.f;
          c4[mi][i] = (r < 130) ? ac0[130 + r] : 0.f;
          sm[mi][i] = 0.f;
        }
        const f16* arow = qb + (m * 16 + mrow) * 64 + quad * 8;
        afr[mi][0] = *(const f16x8*)arow;
        afr[mi][1] = *(const f16x8*)(arow + 32);
      }
    }
    // pass 1: exp-sums (BN z-scores: exp(v) fp32-safe, clamp 80)
#pragma unroll
    for (int mi = 0; mi < 3; mi++) {
      const int m = wv + mi * 4;
      if (m < 9) {
#pragma unroll
        for (int n = 0; n < 9; n++) {
          f16x8 bf0 = *(const f16x8*)&BT[(n * 2 + 0) * FRAG_STRIDE + lane * 8];
          f16x8 bf1 = *(const f16x8*)&BT[(n * 2 + 1) * FRAG_STRIDE + lane * 8];
          f32x4 acc = (f32x4){0.f, 0.f, 0.f, 0.f};
          acc = MFMA16(afr[mi][0], bf0, acc);
          acc = MFMA16(afr[mi][1], bf1, acc);
          const bool valid = (n * 16 + mrow) < 130;
#pragma unroll
          for (int i = 0; i < 4; i++) {
            float v = fminf(a4[mi][i] * acc[i] + c4[mi][i], 80.f);
            if (valid) sm[mi][i] += __expf(v);
          }
        }
#pragma unroll
        for (int i = 0; i < 4; i++) {
#pragma unroll
          for (int msk = 1; msk <= 8; msk <<= 1)
            sm[mi][i] += __shfl_xor(sm[mi][i], msk);
          sm[mi][i] = 1.f / sm[mi][i];
        }
      }
    }
    // pass 2: recompute, emit A f16
#pragma unroll
    for (int mi = 0; mi < 3; mi++) {
      const int m = wv + mi * 4;
      if (m < 9) {
#pragma unroll
        for (int n = 0; n < 9; n++) {
          f16x8 bf0 = *(const f16x8*)&BT[(n * 2 + 0) * FRAG_STRIDE + lane * 8];
          f16x8 bf1 = *(const f16x8*)&BT[(n * 2 + 1) * FRAG_STRIDE + lane * 8];
          f32x4 acc = (f32x4){0.f, 0.f, 0.f, 0.f};
          acc = MFMA16(afr[mi][0], bf0, acc);
          acc = MFMA16(afr[mi][1], bf1, acc);
          const int col = n * 16 + mrow;
#pragma unroll
          for (int i = 0; i < 4; i++) {
            int r = m * 16 + quad * 4 + i;
            if (r < 130) {
              if (col < 130) {
                float v = fminf(a4[mi][i] * acc[i] + c4[mi][i], 80.f);
                Ab[r * 136 + col] = (f16)fmaxf(__expf(v) * sm[mi][i] - thr, 0.f);
              } else if (col < 136) {
                Ab[r * 136 + col] = (f16)0.f;
              }
            }
          }
        }
      }
    }
  }
}

// ---------------- phase: Z = A @ g + b; A-frags direct from global, gT in LDS
template <int FI, int FO, bool RES, bool G1f>
__device__ void gcn_phase(const f16* __restrict__ A16, const float* __restrict__ ZP,
                          const float* __restrict__ ZQ, const f16* __restrict__ xw1,
                          const float* __restrict__ acP, const float* __restrict__ acQ,
                          const float* __restrict__ wmat, const float* __restrict__ bb,
                          float* __restrict__ Zout, float* __restrict__ sp,
                          f16* gT, int bid, int nb, int tid)
{
  const int lane = tid & 63, wv = tid >> 6, mrow = lane & 15, quad = lane >> 4;
  for (int b = bid; b < 4096; b += nb) {
    __syncthreads();                          // protect gT reuse across iters
    for (int i = tid; i < 1344; i += 256) ((float*)gT)[i] = 0.f;
    __syncthreads();
    if constexpr (G1f) {
      for (int i = tid; i < 2080; i += 256) {
        int s = i >> 4, f = i & 15;
        gT[f * 168 + s] = xw1[(size_t)b * 2080 + i];
      }
    } else {
      if (tid < 130) {
        const int r = tid;
        float h[FI];
        const float* zp = ZP + ((size_t)b * 130 + r) * FI;
        const float aP = acP[r], cP = acP[130 + r];
#pragma unroll
        for (int i = 0; i < FI; i++) h[i] = fmaxf(aP * zp[i] + cP, 0.f);
        if constexpr (RES) {
          const float* zq = ZQ + ((size_t)b * 130 + r) * FI;
          const float aQ = acQ[r], cQ = acQ[130 + r];
#pragma unroll
          for (int i = 0; i < FI; i++) h[i] += fmaxf(aQ * zq[i] + cQ, 0.f);
        }
#pragma unroll
        for (int k = 0; k < FO; k++) {
          float s = 0.f;
#pragma unroll
          for (int i = 0; i < FI; i++) s += h[i] * wmat[k * FI + i];
          gT[k * 168 + r] = (f16)s;           // bias NOT here (added post-A)
        }
      }
    }
    __syncthreads();
    f16x8 bfr[5];                             // B-frags cached (k=0..159; >=130 zero)
#pragma unroll
    for (int kk = 0; kk < 5; kk++)
      bfr[kk] = *(const f16x8*)&gT[mrow * 168 + kk * 32 + quad * 8];
    const f16* Ab = A16 + (size_t)b * 17680;
    for (int m = wv; m < 9; m += 4) {
      const f16* arow = Ab + (m * 16 + mrow) * 136 + quad * 8;
      f32x4 acc = (f32x4){0.f, 0.f, 0.f, 0.f};
#pragma unroll
      for (int kk = 0; kk < 5; kk++)          // k>=136 reads next row, B=0 there
        acc = MFMA16(*(const f16x8*)(arow + kk * 32), bfr[kk], acc);
      const int col = mrow;
      const float bk = (col < FO) ? bb[col] : 0.f;
      float p1[4], p2[4];
#pragma unroll
      for (int i = 0; i < 4; i++) {
        int r = m * 16 + quad * 4 + i;
        float v = (col < FO) ? acc[i] + bk : 0.f;
        if (col < FO && r < 130)
          Zout[((size_t)b * 130 + r) * FO + col] = v;
        p1[i] = v; p2[i] = v * v;
      }
#pragma unroll
      for (int i = 0; i < 4; i++)
#pragma unroll
        for (int msk = 1; msk <= 8; msk <<= 1) {
          p1[i] += __shfl_xor(p1[i], msk); p2[i] += __shfl_xor(p2[i], msk);
        }
      if (mrow == 0) {
#pragma unroll
        for (int i = 0; i < 4; i++) {
          int r = m * 16 + quad * 4 + i;
          if (r < 130) {
            sp[(size_t)r * 4096 + b] = p1[i];
            sp[130 * 4096 + (size_t)r * 4096 + b] = p2[i];
          }
        }
      }
    }
  }
}

// ---------------- phase: mlp
__device__ void mlp_phase(const float* __restrict__ Z5, const float* __restrict__ Z6,
                          const float* __restrict__ ac5, const float* __restrict__ ac6,
                          const float* __restrict__ wm, const float* __restrict__ bm,
                          float* __restrict__ out, int bid, int nb, int tid)
{
  const int lane = tid & 63, wv = tid >> 6;
  for (int b = bid * 4 + wv; b < 4096; b += nb * 4) {
    const float* z5 = Z5 + (size_t)b * 260;
    const float* z6 = Z6 + (size_t)b * 260;
    float p0 = 0.f, p1 = 0.f;
#pragma unroll
    for (int j = 0; j < 5; j++) {
      int i = lane + 64 * j;
      if (i < 260) {
        int r = i >> 1;
        float h = fmaxf(ac6[r] * z6[i] + ac6[130 + r], 0.f)
                + fmaxf(ac5[r] * z5[i] + ac5[130 + r], 0.f);
        p0 += h * wm[i];
        p1 += h * wm[260 + i];
      }
    }
#pragma unroll
    for (int m = 1; m <= 32; m <<= 1) { p0 += __shfl_xor(p0, m); p1 += __shfl_xor(p1, m); }
    if (lane == 0) {
      out[(size_t)b * 2] = fmaxf(p0 + bm[0], 0.f);
      out[(size_t)b * 2 + 1] = fmaxf(p1 + bm[1], 0.f);
    }
  }
}

// ---------------- the mega-kernel
__global__ __launch_bounds__(256, 3) void mega(Params P, int nb)
{
  cg::grid_group grid = cg::this_grid();
  __shared__ __align__(16) char smemraw[29696];   // xs(29696B) >= BT(18976B) >= gT >= rr
  f16* xs = (f16*)smemraw;
  f16* BT = (f16*)smemraw;
  f16* gT = (f16*)smemraw;
  float* rr = (float*)smemraw;
  const int bid = blockIdx.x, tid = threadIdx.x;

  // w_prep: [wq(64x200) | w1(16x200)] -> f16 wf[80][224], K zero-pad
  for (int idx = bid * 256 + tid; idx < 80 * 224; idx += nb * 256) {
    int f = idx / 224, k = idx - f * 224;
    float v = 0.f;
    if (k < 200) v = (f < 64) ? P.WQ[f * 200 + k] : P.W1[(f - 64) * 200 + k];
    P.wf[idx] = (f16)v;
  }
  grid.sync();
  kin_phase(P.X, P.wf, P.BQ, P.qk, P.xw1, xs, bid, nb, tid);
  grid.sync();
  relstats_phase(P.qk, P.sp, BT, bid, nb, tid);
  grid.sync();
  stats_phase(P.sp, P.GT, P.BT, 1.f / 532480.f, P.ac, rr, bid, tid);
  grid.sync();
  const float thr = *P.THR;
  asoft_phase(P.qk, P.ac, thr, P.A16, BT, bid, nb, tid);
  grid.sync();
  gcn_phase<16, 16, false, true>(P.A16, nullptr, nullptr, P.xw1, nullptr, nullptr,
                                 nullptr, P.Bb1, P.Z1, P.sp, gT, bid, nb, tid);
  grid.sync();
  stats_phase(P.sp, P.G1, P.BE1, 1.f / 65536.f, P.ac + 260, rr, bid, tid);
  grid.sync();
  gcn_phase<16, 16, false, false>(P.A16, P.Z1, nullptr, nullptr, P.ac + 260, nullptr,
                                  P.W2, P.Bb2, P.Z2, P.sp, gT, bid, nb, tid);
  grid.sync();
  stats_phase(P.sp, P.G2, P.BE2, 1.f / 65536.f, P.ac + 520, rr, bid, tid);
  grid.sync();
  gcn_phase<16, 4, true, false>(P.A16, P.Z2, P.Z1, nullptr, P.ac + 520, P.ac + 260,
                                P.W3, P.Bb3, P.Z3, P.sp, gT, bid, nb, tid);
  grid.sync();
  stats_phase(P.sp, P.G3, P.BE3, 1.f / 16384.f, P.ac + 780, rr, bid, tid);
  grid.sync();
  gcn_phase<4, 4, false, false>(P.A16, P.Z3, nullptr, nullptr, P.ac + 780, nullptr,
                                P.W4, P.Bb4, P.Z4, P.sp, gT, bid, nb, tid);
  grid.sync();
  stats_phase(P.sp, P.G4, P.BE4, 1.f / 16384.f, P.ac + 1040, rr, bid, tid);
  grid.sync();
  gcn_phase<4, 2, true, false>(P.A16, P.Z4, P.Z3, nullptr, P.ac + 1040, P.ac + 780,
                               P.W5, P.Bb5, P.Z5, P.sp, gT, bid, nb, tid);
  grid.sync();
  stats_phase(P.sp, P.G5, P.BE5, 1.f / 8192.f, P.ac + 1300, rr, bid, tid);
  grid.sync();
  gcn_phase<2, 2, false, false>(P.A16, P.Z5, nullptr, nullptr, P.ac + 1300, nullptr,
                                P.W6, P.Bb6, P.Z6, P.sp, gT, bid, nb, tid);
  grid.sync();
  stats_phase(P.sp, P.G6, P.BE6, 1.f / 8192.f, P.ac + 1560, rr, bid, tid);
  grid.sync();
  mlp_phase(P.Z5, P.Z6, P.ac + 1300, P.ac + 1560, P.WM, P.BM, P.out, bid, nb, tid);
}

extern "C" void kernel_launch(void* const* d_in, const int* in_sizes, int n_in,
                              void* d_out, int out_size, void* d_ws, size_t ws_size,
                              hipStream_t stream) {
  Params P;
  P.X   = (const float*)d_in[0];
  P.THR = (const float*)d_in[1];
  P.WQ  = (const float*)d_in[2];
  P.BQ  = (const float*)d_in[3];
  P.GT  = (const float*)d_in[4];
  P.BT  = (const float*)d_in[5];
  P.W1 = (const float*)d_in[6];  P.Bb1 = (const float*)d_in[7];
  P.G1 = (const float*)d_in[8];  P.BE1 = (const float*)d_in[9];
  P.W2 = (const float*)d_in[10]; P.Bb2 = (const float*)d_in[11];
  P.G2 = (const float*)d_in[12]; P.BE2 = (const float*)d_in[13];
  P.W3 = (const float*)d_in[14]; P.Bb3 = (const float*)d_in[15];
  P.G3 = (const float*)d_in[16]; P.BE3 = (const float*)d_in[17];
  P.W4 = (const float*)d_in[18]; P.Bb4 = (const float*)d_in[19];
  P.G4 = (const float*)d_in[20]; P.BE4 = (const float*)d_in[21];
  P.W5 = (const float*)d_in[22]; P.Bb5 = (const float*)d_in[23];
  P.G5 = (const float*)d_in[24]; P.BE5 = (const float*)d_in[25];
  P.W6 = (const float*)d_in[26]; P.Bb6 = (const float*)d_in[27];
  P.G6 = (const float*)d_in[28]; P.BE6 = (const float*)d_in[29];
  P.WM = (const float*)d_in[30]; P.BM = (const float*)d_in[31];

  float* ws = (float*)d_ws;
  // Workspace (float units). Total ~82.0M floats = 328 MB.
  P.A16  = (f16*)ws;                          // 4096*130*136 halfs
  P.qk   = (f16*)(ws + 36208640);             // 532480*64 halfs
  P.xw1  = (f16*)(ws + 53248000);             // 532480*16 halfs
  P.wf   = (f16*)(ws + 57507840);             // 80*224 halfs (8960 fl)
  P.Z1 = ws + 57516800;
  P.Z2 = ws + 66036480;
  P.Z3 = ws + 74556160;
  P.Z4 = ws + 76686080;
  P.Z5 = ws + 78816000;
  P.Z6 = ws + 79880960;
  P.sp = ws + 80945920;
  P.ac = ws + 82010880;
  P.out = (float*)d_out;

  int occ = 0;
  hipError_t e = hipOccupancyMaxActiveBlocksPerMultiprocessor(&occ, mega, 256, 0);
  if (e != hipSuccess || occ < 1) occ = 1;
  int nb = occ * 256;                         // MI355X: 256 CUs
  if (nb > 4096) nb = 4096;
  void* args[] = { (void*)&P, (void*)&nb };
  hipLaunchCooperativeKernel((void*)mega, dim3(nb), dim3(256), args, 0, stream);
}

// Round 3
// 1118.348 us; speedup vs baseline: 2.2510x; 1.9704x over previous
//
#include <hip/hip_runtime.h>
#include <math.h>

// B=4096, R=130, T=200, Q=64. f16 MFMA 16x16x32 everywhere, fp32 accum/stats.
// R6: revert to proven R3 multi-kernel pipeline (1136us) + surgical ILP fixes:
//  - k_gcn: m-loop statically unrolled, all 15 A-frag loads hoisted pre-MFMA.
//  - k_relstats: af0/af1 loads for all 3 m-tiles hoisted.
//  - k_Asoft: no-max-sub 2-phase softmax (BN z-scores, clamp 80; proven R5),
//    single MFMA pass kept (acc[9]).

typedef _Float16 f16;
typedef _Float16 f16x8 __attribute__((ext_vector_type(8)));
typedef _Float16 f16x4 __attribute__((ext_vector_type(4)));
typedef float f32x4 __attribute__((ext_vector_type(4)));

#define MFMA16(a, b, c) __builtin_amdgcn_mfma_f32_16x16x32_f16((a), (b), (c), 0, 0, 0)

// ---------------- w_prep: [wq(64x200) | w1(16x200)] -> f16 wf[80][224], K zero-pad
__global__ __launch_bounds__(256) void w_prep(
    const float* __restrict__ wq, const float* __restrict__ w1, f16* __restrict__ wf)
{
  const int f = blockIdx.x;                   // 80 blocks
  const int k = threadIdx.x;
  if (k < 224) {
    float v = 0.f;
    if (k < 200) v = (f < 64) ? wq[f * 200 + k] : w1[(f - 64) * 200 + k];
    wf[f * 224 + k] = (f16)v;
  }
}

// ---------------- k_in: X(532480x200) @ wf^T -> qk f16 (B,130,64), xw1 f16 (B,130,16)
__global__ __launch_bounds__(256) void k_in(
    const float* __restrict__ x, const f16* __restrict__ wf,
    const float* __restrict__ bq, f16* __restrict__ qk, f16* __restrict__ xw1)
{
  __shared__ f16 xs[64 * 232];                // stride 232 halves = 464B == 20 banks: 2-way free
  const int tid = threadIdx.x;
  const size_t m0 = (size_t)blockIdx.x * 64;  // 8320 blocks
  {                                           // zero K-pad cols 200..231 (exactly 256 stores)
    int r = tid >> 2, j = tid & 3;
    *(float4*)&xs[r * 232 + 200 + j * 8] = make_float4(0, 0, 0, 0);
  }
  const float4* xsrc = (const float4*)(x + m0 * 200);
  for (int i = tid; i < 3200; i += 256) {     // NaN-clean + cvt f16
    int r = i / 50, c = i - (i / 50) * 50;
    float4 v = xsrc[i];
    v.x = (v.x != v.x) ? 0.f : v.x;
    v.y = (v.y != v.y) ? 0.f : v.y;
    v.z = (v.z != v.z) ? 0.f : v.z;
    v.w = (v.w != v.w) ? 0.f : v.w;
    f16x4 h; h[0] = (f16)v.x; h[1] = (f16)v.y; h[2] = (f16)v.z; h[3] = (f16)v.w;
    *(f16x4*)&xs[r * 232 + c * 4] = h;
  }
  __syncthreads();
  const int lane = tid & 63, wv = tid >> 6;
  const int mrow = lane & 15, quad = lane >> 4;
  f32x4 acc[5];
#pragma unroll
  for (int n = 0; n < 5; n++) acc[n] = (f32x4){0.f, 0.f, 0.f, 0.f};
  const f16* xrow = &xs[(wv * 16 + mrow) * 232 + quad * 8];
  const f16* wrow = wf + mrow * 224 + quad * 8;   // B-frags from global (L2-hot)
#pragma unroll
  for (int k0 = 0; k0 < 224; k0 += 32) {
    f16x8 af = *(const f16x8*)(xrow + k0);
#pragma unroll
    for (int n = 0; n < 5; n++)
      acc[n] = MFMA16(af, *(const f16x8*)(wrow + n * 3584 + k0), acc[n]);
  }
  const size_t rbase = m0 + wv * 16;
#pragma unroll
  for (int n = 0; n < 4; n++) {               // qk (+bq)
    int col = n * 16 + mrow;
    float bqv = bq[col];
#pragma unroll
    for (int i = 0; i < 4; i++)
      qk[(rbase + quad * 4 + i) * 64 + col] = (f16)(acc[n][i] + bqv);
  }
#pragma unroll
  for (int i = 0; i < 4; i++)                 // xw1, no bias (added post-A-matmul)
    xw1[(rbase + quad * 4 + i) * 16 + mrow] = (f16)acc[4][i];
}

// Gather the 18 B-fragments (9 n-tiles x 2 k-halves) for the reshape-K matmul.
// B[k=q][n-col=s]: element = flat[q*130+s]; s>=130 -> 0.
__device__ __forceinline__ void gather_bfrags(const f16* qf, int mrow, int quad,
                                              f16x8 bf[9][2])
{
#pragma unroll
  for (int n = 0; n < 9; n++) {
    const int s = n * 16 + mrow;
    const bool ok = (s < 130);
#pragma unroll
    for (int kh = 0; kh < 2; kh++) {
      f16x8 t;
#pragma unroll
      for (int j = 0; j < 8; j++) {
        int q = kh * 32 + quad * 8 + j;
        t[j] = ok ? qf[q * 130 + s] : (f16)0.f;
      }
      bf[n][kh] = t;
    }
  }
}

// ---------------- k_relstats: rel tiles (MFMA), emit BN partial sums only
__global__ __launch_bounds__(256) void k_relstats(
    const f16* __restrict__ qk, float* __restrict__ sp)
{
  __shared__ f16 qf[8320];                    // flat per-batch qk (16.6 KB)
  const int b = blockIdx.x, tid = threadIdx.x;
  const f16* qb = qk + (size_t)b * 8320;
  for (int i = tid; i < 1040; i += 256)
    *(f16x8*)&qf[i * 8] = *(const f16x8*)(qb + i * 8);
  __syncthreads();
  const int lane = tid & 63, wv = tid >> 6, mrow = lane & 15, quad = lane >> 4;
  f16x8 bf[9][2];
  gather_bfrags(qf, mrow, quad, bf);
  // hoist A-frag loads for all 3 m-tiles (memory ILP)
  f16x8 afr[3][2];
#pragma unroll
  for (int mi = 0; mi < 3; mi++) {
    const int m = wv + mi * 4;
    if (m < 9) {
      const f16* arow = qb + (m * 16 + mrow) * 64 + quad * 8;
      afr[mi][0] = *(const f16x8*)arow;
      afr[mi][1] = *(const f16x8*)(arow + 32);
    }
  }
#pragma unroll
  for (int mi = 0; mi < 3; mi++) {
    const int m = wv + mi * 4;
    if (m >= 9) continue;
    float p1[4] = {0, 0, 0, 0}, p2[4] = {0, 0, 0, 0};
#pragma unroll
    for (int n = 0; n < 9; n++) {
      f32x4 acc = (f32x4){0.f, 0.f, 0.f, 0.f};
      acc = MFMA16(afr[mi][0], bf[n][0], acc);
      acc = MFMA16(afr[mi][1], bf[n][1], acc);
#pragma unroll
      for (int i = 0; i < 4; i++) { float v = acc[i]; p1[i] += v; p2[i] += v * v; }
    }
#pragma unroll
    for (int i = 0; i < 4; i++)
#pragma unroll
      for (int msk = 1; msk <= 8; msk <<= 1) {
        p1[i] += __shfl_xor(p1[i], msk); p2[i] += __shfl_xor(p2[i], msk);
      }
    if (mrow == 0) {
#pragma unroll
      for (int i = 0; i < 4; i++) {
        int r = m * 16 + quad * 4 + i;
        if (r < 130) {
          sp[(size_t)r * 4096 + b] = p1[i];
          sp[130 * 4096 + (size_t)r * 4096 + b] = p2[i];
        }
      }
    }
  }
}

// ---------------- k_stats: reduce partials -> affine a,c
__global__ __launch_bounds__(256) void k_stats(
    const float* __restrict__ sp, const float* __restrict__ g,
    const float* __restrict__ beta, float invN, float* __restrict__ ac)
{
  const int r = blockIdx.x, tid = threadIdx.x;
  float s1 = 0.f, s2 = 0.f;
  const float* p1 = sp + (size_t)r * 4096;
  const float* p2 = sp + 130 * 4096 + (size_t)r * 4096;
  for (int j = tid; j < 4096; j += 256) { s1 += p1[j]; s2 += p2[j]; }
#pragma unroll
  for (int m = 1; m <= 32; m <<= 1) { s1 += __shfl_xor(s1, m); s2 += __shfl_xor(s2, m); }
  __shared__ float r1[4], r2[4];
  if ((tid & 63) == 0) { r1[tid >> 6] = s1; r2[tid >> 6] = s2; }
  __syncthreads();
  if (tid == 0) {
    float S1 = r1[0] + r1[1] + r1[2] + r1[3];
    float S2 = r2[0] + r2[1] + r2[2] + r2[3];
    float mean = S1 * invN;
    float var = S2 * invN - mean * mean;
    float a = g[r] * rsqrtf(var + 1e-5f);
    ac[r] = a;
    ac[130 + r] = beta[r] - mean * a;
  }
}

// ---------------- k_Asoft: rel (1 MFMA pass, 9 acc tiles in regs), affine,
// 2-phase no-max softmax (BN z-scores, clamp 80), relu(x-thr),
// A -> f16 [b][130][136] (cols 130-135 zeroed)
__global__ __launch_bounds__(256) void k_Asoft(
    const f16* __restrict__ qk, const float* __restrict__ ac0,
    const float* __restrict__ thrp, f16* __restrict__ A16)
{
  __shared__ f16 qf[8320];
  const int b = blockIdx.x, tid = threadIdx.x;
  const f16* qb = qk + (size_t)b * 8320;
  for (int i = tid; i < 1040; i += 256)
    *(f16x8*)&qf[i * 8] = *(const f16x8*)(qb + i * 8);
  __syncthreads();
  const float thr = *thrp;
  const int lane = tid & 63, wv = tid >> 6, mrow = lane & 15, quad = lane >> 4;
  f16x8 bf[9][2];
  gather_bfrags(qf, mrow, quad, bf);
  f16* Ab = A16 + (size_t)b * 17680;          // row stride 136
  for (int m = wv; m < 9; m += 4) {
    float a4[4], c4[4];
#pragma unroll
    for (int i = 0; i < 4; i++) {
      int r = m * 16 + quad * 4 + i;
      a4[i] = (r < 130) ? ac0[r] : 0.f;
      c4[i] = (r < 130) ? ac0[130 + r] : 0.f;
    }
    const f16* arow = qb + (m * 16 + mrow) * 64 + quad * 8;
    f16x8 af0 = *(const f16x8*)arow;
    f16x8 af1 = *(const f16x8*)(arow + 32);
    f32x4 acc[9];
#pragma unroll
    for (int n = 0; n < 9; n++) {
      acc[n] = (f32x4){0.f, 0.f, 0.f, 0.f};
      acc[n] = MFMA16(af0, bf[n][0], acc[n]);
      acc[n] = MFMA16(af1, bf[n][1], acc[n]);
    }
    // phase 1: exp-sums without max subtraction (values are BN z-scores)
    float sm[4] = {0.f, 0.f, 0.f, 0.f};
#pragma unroll
    for (int n = 0; n < 9; n++) {
      const bool valid = (n * 16 + mrow) < 130;
#pragma unroll
      for (int i = 0; i < 4; i++) {
        float v = fminf(a4[i] * acc[n][i] + c4[i], 80.f);
        if (valid) sm[i] += __expf(v);
      }
    }
#pragma unroll
    for (int i = 0; i < 4; i++) {             // 16-lane sum reduce
#pragma unroll
      for (int msk = 1; msk <= 8; msk <<= 1)
        sm[i] += __shfl_xor(sm[i], msk);
      sm[i] = 1.f / sm[i];
    }
    // phase 2: emit A f16
#pragma unroll
    for (int n = 0; n < 9; n++) {
      const int col = n * 16 + mrow;
#pragma unroll
      for (int i = 0; i < 4; i++) {
        int r = m * 16 + quad * 4 + i;
        if (r < 130) {
          if (col < 130) {
            float v = fminf(a4[i] * acc[n][i] + c4[i], 80.f);
            Ab[r * 136 + col] = (f16)fmaxf(__expf(v) * sm[i] - thr, 0.f);
          } else if (col < 136) {
            Ab[r * 136 + col] = (f16)0.f;
          }
        }
      }
    }
  }
}

// ---------------- k_gcn: Z = A @ g + b; A-frags hoisted (3 m-tiles prefetched),
// gT in LDS
template <int FI, int FO, bool RES, bool G1>
__global__ __launch_bounds__(256) void k_gcn(
    const f16* __restrict__ A16, const float* __restrict__ ZP,
    const float* __restrict__ ZQ, const f16* __restrict__ xw1,
    const float* __restrict__ acP, const float* __restrict__ acQ,
    const float* __restrict__ wmat, const float* __restrict__ bb,
    float* __restrict__ Zout, float* __restrict__ sp)
{
  __shared__ f16 gT[16 * 168];                // [n][s], stride 168 (2-way free), zero-pad
  const int b = blockIdx.x, tid = threadIdx.x;
  for (int i = tid; i < 1344; i += 256) ((float*)gT)[i] = 0.f;
  __syncthreads();
  if constexpr (G1) {
    for (int i = tid; i < 2080; i += 256) {
      int s = i >> 4, f = i & 15;
      gT[f * 168 + s] = xw1[(size_t)b * 2080 + i];
    }
  } else {
    if (tid < 130) {
      const int r = tid;
      float h[FI];
      const float* zp = ZP + ((size_t)b * 130 + r) * FI;
      const float aP = acP[r], cP = acP[130 + r];
#pragma unroll
      for (int i = 0; i < FI; i++) h[i] = fmaxf(aP * zp[i] + cP, 0.f);
      if constexpr (RES) {
        const float* zq = ZQ + ((size_t)b * 130 + r) * FI;
        const float aQ = acQ[r], cQ = acQ[130 + r];
#pragma unroll
        for (int i = 0; i < FI; i++) h[i] += fmaxf(aQ * zq[i] + cQ, 0.f);
      }
#pragma unroll
      for (int k = 0; k < FO; k++) {
        float s = 0.f;
#pragma unroll
        for (int i = 0; i < FI; i++) s += h[i] * wmat[k * FI + i];
        gT[k * 168 + r] = (f16)s;             // bias NOT here (added post-A)
      }
    }
  }
  __syncthreads();
  const int lane = tid & 63, wv = tid >> 6, mrow = lane & 15, quad = lane >> 4;
  f16x8 bfr[5];                               // B-frags cached (k = 0..159; >=130 zero)
#pragma unroll
  for (int kk = 0; kk < 5; kk++)
    bfr[kk] = *(const f16x8*)&gT[mrow * 168 + kk * 32 + quad * 8];
  const f16* Ab = A16 + (size_t)b * 17680;
  // hoist ALL A-frag loads (3 m-tiles x 5) before any MFMA: 15 loads in flight
  f16x8 afr[3][5];
#pragma unroll
  for (int mi = 0; mi < 3; mi++) {
    const int m = wv + mi * 4;
    if (m < 9) {
      const f16* arow = Ab + (m * 16 + mrow) * 136 + quad * 8;
#pragma unroll
      for (int kk = 0; kk < 5; kk++)          // k>=136 reads next row, B=0 there
        afr[mi][kk] = *(const f16x8*)(arow + kk * 32);
    }
  }
#pragma unroll
  for (int mi = 0; mi < 3; mi++) {
    const int m = wv + mi * 4;
    if (m >= 9) continue;
    f32x4 acc = (f32x4){0.f, 0.f, 0.f, 0.f};
#pragma unroll
    for (int kk = 0; kk < 5; kk++)
      acc = MFMA16(afr[mi][kk], bfr[kk], acc);
    const int col = mrow;
    const float bk = (col < FO) ? bb[col] : 0.f;
    float p1[4], p2[4];
#pragma unroll
    for (int i = 0; i < 4; i++) {
      int r = m * 16 + quad * 4 + i;
      float v = (col < FO) ? acc[i] + bk : 0.f;
      if (col < FO && r < 130)
        Zout[((size_t)b * 130 + r) * FO + col] = v;
      p1[i] = v; p2[i] = v * v;
    }
#pragma unroll
    for (int i = 0; i < 4; i++)
#pragma unroll
      for (int msk = 1; msk <= 8; msk <<= 1) {
        p1[i] += __shfl_xor(p1[i], msk); p2[i] += __shfl_xor(p2[i], msk);
      }
    if (mrow == 0) {
#pragma unroll
      for (int i = 0; i < 4; i++) {
        int r = m * 16 + quad * 4 + i;
        if (r < 130) {
          sp[(size_t)r * 4096 + b] = p1[i];
          sp[130 * 4096 + (size_t)r * 4096 + b] = p2[i];
        }
      }
    }
  }
}

// ---------------- k_mlp
__global__ __launch_bounds__(256) void k_mlp(
    const float* __restrict__ Z5, const float* __restrict__ Z6,
    const float* __restrict__ ac5, const float* __restrict__ ac6,
    const float* __restrict__ wm, const float* __restrict__ bm, float* __restrict__ out)
{
  const int tid = threadIdx.x, lane = tid & 63, wv = tid >> 6;
  const int b = blockIdx.x * 4 + wv;
  const float* z5 = Z5 + (size_t)b * 260;
  const float* z6 = Z6 + (size_t)b * 260;
  float p0 = 0.f, p1 = 0.f;
#pragma unroll
  for (int j = 0; j < 5; j++) {
    int i = lane + 64 * j;
    if (i < 260) {
      int r = i >> 1;
      float h = fmaxf(ac6[r] * z6[i] + ac6[130 + r], 0.f)
              + fmaxf(ac5[r] * z5[i] + ac5[130 + r], 0.f);
      p0 += h * wm[i];
      p1 += h * wm[260 + i];
    }
  }
#pragma unroll
  for (int m = 1; m <= 32; m <<= 1) { p0 += __shfl_xor(p0, m); p1 += __shfl_xor(p1, m); }
  if (lane == 0) {
    out[(size_t)b * 2] = fmaxf(p0 + bm[0], 0.f);
    out[(size_t)b * 2 + 1] = fmaxf(p1 + bm[1], 0.f);
  }
}

extern "C" void kernel_launch(void* const* d_in, const int* in_sizes, int n_in,
                              void* d_out, int out_size, void* d_ws, size_t ws_size,
                              hipStream_t stream) {
  const float* X   = (const float*)d_in[0];
  const float* THR = (const float*)d_in[1];
  const float* WQ  = (const float*)d_in[2];
  const float* BQ  = (const float*)d_in[3];
  const float* GT  = (const float*)d_in[4];
  const float* BT  = (const float*)d_in[5];
  const float* W1 = (const float*)d_in[6];  const float* Bb1 = (const float*)d_in[7];
  const float* G1g = (const float*)d_in[8]; const float* BE1 = (const float*)d_in[9];
  const float* W2 = (const float*)d_in[10]; const float* Bb2 = (const float*)d_in[11];
  const float* G2 = (const float*)d_in[12]; const float* BE2 = (const float*)d_in[13];
  const float* W3 = (const float*)d_in[14]; const float* Bb3 = (const float*)d_in[15];
  const float* G3 = (const float*)d_in[16]; const float* BE3 = (const float*)d_in[17];
  const float* W4 = (const float*)d_in[18]; const float* Bb4 = (const float*)d_in[19];
  const float* G4 = (const float*)d_in[20]; const float* BE4 = (const float*)d_in[21];
  const float* W5 = (const float*)d_in[22]; const float* Bb5 = (const float*)d_in[23];
  const float* G5 = (const float*)d_in[24]; const float* BE5 = (const float*)d_in[25];
  const float* W6 = (const float*)d_in[26]; const float* Bb6 = (const float*)d_in[27];
  const float* G6 = (const float*)d_in[28]; const float* BE6 = (const float*)d_in[29];
  const float* WM = (const float*)d_in[30]; const float* BM = (const float*)d_in[31];

  float* ws = (float*)d_ws;
  // Workspace (float units). Total ~82.0M floats = 328 MB.
  f16*   A16   = (f16*)ws;                    // 4096*130*136 halfs
  f16*   qk16  = (f16*)(ws + 36208640);       // 532480*64 halfs
  f16*   xw116 = (f16*)(ws + 53248000);       // 532480*16 halfs
  f16*   wf16  = (f16*)(ws + 57507840);       // 80*224 halfs (8960 fl)
  float* Z1 = ws + 57516800;
  float* Z2 = ws + 66036480;
  float* Z3 = ws + 74556160;
  float* Z4 = ws + 76686080;
  float* Z5 = ws + 78816000;
  float* Z6 = ws + 79880960;
  float* sp = ws + 80945920;
  float* ac = ws + 82010880;

  w_prep<<<80, 256, 0, stream>>>(WQ, W1, wf16);
  k_in<<<8320, 256, 0, stream>>>(X, wf16, BQ, qk16, xw116);
  k_relstats<<<4096, 256, 0, stream>>>(qk16, sp);
  k_stats<<<130, 256, 0, stream>>>(sp, GT, BT, 1.f / 532480.f, ac);
  k_Asoft<<<4096, 256, 0, stream>>>(qk16, ac, THR, A16);
  k_gcn<16, 16, false, true><<<4096, 256, 0, stream>>>(A16, nullptr, nullptr, xw116,
      nullptr, nullptr, nullptr, Bb1, Z1, sp);
  k_stats<<<130, 256, 0, stream>>>(sp, G1g, BE1, 1.f / 65536.f, ac + 260);
  k_gcn<16, 16, false, false><<<4096, 256, 0, stream>>>(A16, Z1, nullptr, nullptr,
      ac + 260, nullptr, W2, Bb2, Z2, sp);
  k_stats<<<130, 256, 0, stream>>>(sp, G2, BE2, 1.f / 65536.f, ac + 520);
  k_gcn<16, 4, true, false><<<4096, 256, 0, stream>>>(A16, Z2, Z1, nullptr,
      ac + 520, ac + 260, W3, Bb3, Z3, sp);
  k_stats<<<130, 256, 0, stream>>>(sp, G3, BE3, 1.f / 16384.f, ac + 780);
  k_gcn<4, 4, false, false><<<4096, 256, 0, stream>>>(A16, Z3, nullptr, nullptr,
      ac + 780, nullptr, W4, Bb4, Z4, sp);
  k_stats<<<130, 256, 0, stream>>>(sp, G4, BE4, 1.f / 16384.f, ac + 1040);
  k_gcn<4, 2, true, false><<<4096, 256, 0, stream>>>(A16, Z4, Z3, nullptr,
      ac + 1040, ac + 780, W5, Bb5, Z5, sp);
  k_stats<<<130, 256, 0, stream>>>(sp, G5, BE5, 1.f / 8192.f, ac + 1300);
  k_gcn<2, 2, false, false><<<4096, 256, 0, stream>>>(A16, Z5, nullptr, nullptr,
      ac + 1300, nullptr, W6, Bb6, Z6, sp);
  k_stats<<<130, 256, 0, stream>>>(sp, G6, BE6, 1.f / 8192.f, ac + 1560);
  k_mlp<<<1024, 256, 0, stream>>>(Z5, Z6, ac + 1300, ac + 1560, WM, BM, (float*)d_out);
}